// Round 10
// baseline (10768.694 us; speedup 1.0000x reference)
//
#include <hip/hip_runtime.h>
#include <hip/hip_bf16.h>

// SP_DecoderLight forward, MI355X. Round 10: R9 + AVX512 npyv pairwise sq.
// sq feeds ONLY the ranking; R7->R8 proved flips respond to sq tree. Host is
// Zen4/5 EPYC -> numpy runtime dispatch = AVX512 (npyv 16-lane): 4x16 accs
// (c=64i+16v+l), combine (r0+r1)+(r2+r3), then _mm512_reduce_add_ps tree
// b[l]=u[l]+u[l+8]; c[l]=b[l]+b[l+4]; d[l]=c[l]+c[l+2]; d0+d1.
// Head/gram: sequential-c FMA chains (width-independent) -- R9, kept.

using bf16 = __hip_bfloat16;

// ---------------- np-exact sequential GEMM (FMA chain, c-ascending) -------
template<int ACT, int OG>
__global__ __launch_bounds__(256) void seqmm_k(
    const float* __restrict__ W, const float* __restrict__ X,
    const float* __restrict__ bias, float* __restrict__ Out,
    int C, long sXb, long sOb)
{
  int n = blockIdx.x * 256 + threadIdx.x;   // 2048 cols
  int o0 = blockIdx.y * OG;
  const float* Xb = X + (long)blockIdx.z * sXb;
  float acc[OG];
#pragma unroll
  for (int g = 0; g < OG; ++g) acc[g] = 0.f;
  for (int c = 0; c < C; ++c) {
    float xv = Xb[(long)c * 2048 + n];
#pragma unroll
    for (int g = 0; g < OG; ++g)
      acc[g] = fmaf(W[(long)(o0 + g) * C + c], xv, acc[g]);
  }
  float* Ob = Out + (long)blockIdx.z * sOb;
#pragma unroll
  for (int g = 0; g < OG; ++g) {
    float v = __fadd_rn(acc[g], bias[o0 + g]);
    if (ACT) v = v >= 0.f ? v : __fmul_rn(0.01f, v);
    Ob[(long)(o0 + g) * 2048 + n] = v;
  }
}

// numpy npyv(AVX512) pairwise sum of squares over 128 (c-strided source):
// 4 accs x 16 lanes, c = 64*i + 16*v + l (i=0 init, i=1 add);
// u = (r0+r1)+(r2+r3); then reduce_add tree (stride-halving).
__global__ void sqnp_k(const float* __restrict__ x1, float* __restrict__ sq) {
  int n = blockIdx.x * 256 + threadIdx.x;
  int b = blockIdx.y;
  const float* p = x1 + (long)b * 128 * 2048 + n;
  float r[4][16];
#pragma unroll
  for (int v = 0; v < 4; ++v)
#pragma unroll
    for (int l = 0; l < 16; ++l) {
      float x = p[(long)(16 * v + l) * 2048];
      r[v][l] = __fmul_rn(x, x);            // tmp = xt*xt rounded first
    }
#pragma unroll
  for (int v = 0; v < 4; ++v)
#pragma unroll
    for (int l = 0; l < 16; ++l) {
      float x = p[(long)(64 + 16 * v + l) * 2048];
      r[v][l] = __fadd_rn(r[v][l], __fmul_rn(x, x));
    }
  float u[16];
#pragma unroll
  for (int l = 0; l < 16; ++l)
    u[l] = __fadd_rn(__fadd_rn(r[0][l], r[1][l]), __fadd_rn(r[2][l], r[3][l]));
  float b8[8];
#pragma unroll
  for (int l = 0; l < 8; ++l) b8[l] = __fadd_rn(u[l], u[l + 8]);
  float c4[4];
#pragma unroll
  for (int l = 0; l < 4; ++l) c4[l] = __fadd_rn(b8[l], b8[l + 4]);
  float d0 = __fadd_rn(c4[0], c4[2]);
  float d1 = __fadd_rn(c4[1], c4[3]);
  sq[b * 2048 + n] = __fadd_rn(d0, d1);
}

// np-exact gram (FMA chain): g[n,m] = sum_c fma; D = (sq[n]+sq[m]) - 2*g
__global__ __launch_bounds__(256) void gramseq_k(const float* __restrict__ A,
                                                 const float* __restrict__ sqb,
                                                 float* __restrict__ D) {
  int m = blockIdx.x * 256 + threadIdx.x;
  int n0 = blockIdx.y * 8;
  float g[8];
#pragma unroll
  for (int j = 0; j < 8; ++j) g[j] = 0.f;
  for (int c = 0; c < 128; ++c) {
    float xm = A[(long)c * 2048 + m];
#pragma unroll
    for (int j = 0; j < 8; ++j)
      g[j] = fmaf(A[(long)c * 2048 + n0 + j], xm, g[j]);
  }
  float sm = sqb[m];
#pragma unroll
  for (int j = 0; j < 8; ++j) {
    float t1 = __fadd_rn(sqb[n0 + j], sm);
    D[(long)(n0 + j) * 2048 + m] = __fsub_rn(t1, __fmul_rn(2.0f, g[j]));
  }
}

// ---------------- f32 tiled GEMM (downstream) ----------------
template<int XMODE, int ACT, int STATS>
__global__ __launch_bounds__(256) void gemm_k(
    const float* __restrict__ W, const float* __restrict__ X,
    const float* __restrict__ bias, float* __restrict__ Out,
    int O, int K, int N, long sXb, long sOb,
    const float* __restrict__ rsc, const float* __restrict__ rsh, float slope,
    const int* __restrict__ idxp, long sIb,
    double* __restrict__ gsum, double* __restrict__ gsq)
{
  const float* Xb = X + (long)blockIdx.z * sXb;
  int n0 = blockIdx.x * 64, o0 = blockIdx.y * 64;
  __shared__ float Ws[16][68];
  __shared__ float Xs[16][68];
  __shared__ int ncol[64], jcol[64];
  __shared__ float ssum[64], ssq[64];
  int t = threadIdx.x, tx = t & 15, ty = t >> 4;
  if constexpr (XMODE == 2) {
    if (t < 64) {
      int m = n0 + t;
      ncol[t] = m / 10;
      jcol[t] = idxp[(long)blockIdx.z * sIb + m];
    }
    __syncthreads();
  }
  float acc[16] = {};
  for (int k0 = 0; k0 < K; k0 += 16) {
#pragma unroll
    for (int i = 0; i < 4; ++i) {
      int l = t + i * 256, oo = l >> 4, kk = l & 15;
      int o = o0 + oo, k = k0 + kk;
      float v = 0.f;
      if (o < O && k < K) v = W[(long)o * K + k];
      Ws[kk][oo] = v;
    }
#pragma unroll
    for (int i = 0; i < 4; ++i) {
      int kk = (t >> 6) + i * 4, nn = t & 63;
      int k = k0 + kk;
      float v = 0.f;
      if (k < K) {
        if constexpr (XMODE == 2) {
          v = Xb[(long)k * 2048 + jcol[nn]] - Xb[(long)k * 2048 + ncol[nn]];
          v = fmaf(rsc[k], v, rsh[k]);
          v = v >= 0.f ? v : 0.01f * v;
        } else {
          v = Xb[(long)k * N + n0 + nn];
        }
      }
      Xs[kk][nn] = v;
    }
    __syncthreads();
#pragma unroll
    for (int kk = 0; kk < 16; ++kk) {
      float a0 = Ws[kk][ty * 4 + 0], a1 = Ws[kk][ty * 4 + 1];
      float a2 = Ws[kk][ty * 4 + 2], a3 = Ws[kk][ty * 4 + 3];
      float b0 = Xs[kk][tx * 4 + 0], b1 = Xs[kk][tx * 4 + 1];
      float b2 = Xs[kk][tx * 4 + 2], b3 = Xs[kk][tx * 4 + 3];
      acc[0] = fmaf(a0, b0, acc[0]);   acc[1] = fmaf(a0, b1, acc[1]);
      acc[2] = fmaf(a0, b2, acc[2]);   acc[3] = fmaf(a0, b3, acc[3]);
      acc[4] = fmaf(a1, b0, acc[4]);   acc[5] = fmaf(a1, b1, acc[5]);
      acc[6] = fmaf(a1, b2, acc[6]);   acc[7] = fmaf(a1, b3, acc[7]);
      acc[8] = fmaf(a2, b0, acc[8]);   acc[9] = fmaf(a2, b1, acc[9]);
      acc[10] = fmaf(a2, b2, acc[10]); acc[11] = fmaf(a2, b3, acc[11]);
      acc[12] = fmaf(a3, b0, acc[12]); acc[13] = fmaf(a3, b1, acc[13]);
      acc[14] = fmaf(a3, b2, acc[14]); acc[15] = fmaf(a3, b3, acc[15]);
    }
    __syncthreads();
  }
  if constexpr (STATS) {
    if (t < 64) { ssum[t] = 0.f; ssq[t] = 0.f; }
    __syncthreads();
#pragma unroll
    for (int i = 0; i < 4; ++i) {
      float s = 0.f, s2 = 0.f;
#pragma unroll
      for (int j = 0; j < 4; ++j) { float v = acc[i * 4 + j]; s += v; s2 = fmaf(v, v, s2); }
      atomicAdd(&ssum[ty * 4 + i], s);
      atomicAdd(&ssq[ty * 4 + i], s2);
    }
    __syncthreads();
    if (t < 64) {
      atomicAdd(&gsum[o0 + t], (double)ssum[t]);
      atomicAdd(&gsq[o0 + t], (double)ssq[t]);
    }
  } else {
    float* Ob = Out + (long)blockIdx.z * sOb;
#pragma unroll
    for (int i = 0; i < 4; ++i) {
      int o = o0 + ty * 4 + i;
      if (o < O) {
        float bv = bias ? bias[o] : 0.f;
#pragma unroll
        for (int j = 0; j < 4; ++j) {
          float v = acc[i * 4 + j] + bv;
          if constexpr (ACT == 1) v = v >= 0.f ? v : slope * v;
          if constexpr (ACT == 2) v = tanhf(v);
          Ob[(long)o * N + n0 + tx * 4 + j] = v;
        }
      }
    }
  }
}

// ---------------- small kernels ----------------
__global__ void fill_k(float* __restrict__ out, float v, int n) {
  int id = blockIdx.x * 256 + threadIdx.x;
  if (id < n) out[id] = v;
}

__global__ void xz_k(const float* __restrict__ x, const float* __restrict__ z,
                     float* __restrict__ xz) {
  long id = (long)blockIdx.x * 256 + threadIdx.x;
  const long TOT = 8L * 131 * 2048;
  if (id >= TOT) return;
  int n = (int)(id % 2048);
  int c = (int)((id / 2048) % 131);
  int b = (int)(id / (131L * 2048));
  float v = (c < 3) ? x[((long)b * 3 + c) * 2048 + n]
                    : z[((long)b * 128 + (c - 3)) * 2048 + n];
  xz[id] = v;
}

__global__ void xwsplit_k(const float* __restrict__ xw, float* __restrict__ A,
                          float* __restrict__ Bm) {
  int id = blockIdx.x * 256 + threadIdx.x;       // 512*128
  if (id >= 512 * 128) return;
  int o = id / 128, c = id % 128;
  float a = xw[o * 256 + c];
  float b = xw[o * 256 + 128 + c];
  A[id] = a - b;
  Bm[id] = b;
}

// per-batch: 11 smallest ascending (stable tie-break by index); rank0=self.
__global__ __launch_bounds__(64) void topk_k(const float* __restrict__ dist,
                                             int* __restrict__ idx) {
  int n = blockIdx.x;
  const float* row = dist + (long)n * 2048;
  __shared__ float vals[2048];
  int lane = threadIdx.x;
  for (int i = lane; i < 2048; i += 64) vals[i] = row[i];
  __syncthreads();
  const float INF = __builtin_inff();
  for (int r = 0; r < 11; ++r) {
    float v = INF; int mi = 0x7fffffff;
    for (int i = lane; i < 2048; i += 64) {
      float xv = vals[i];
      if (xv < v) { v = xv; mi = i; }
    }
    for (int off = 32; off; off >>= 1) {
      float ov = __shfl_xor(v, off);
      int om = __shfl_xor(mi, off);
      if (ov < v || (ov == v && om < mi)) { v = ov; mi = om; }
    }
    if (mi < 0 || mi > 2047) mi = n;     // defensive: degrade, don't fault
    if (lane == 0) {
      if (r > 0) idx[n * 10 + (r - 1)] = mi;
      vals[mi] = INF;
    }
    __syncthreads();
  }
}

// BN1 stats of virtual cw1[b][c][n][k] = Q[b][c][idx]-Q[b][c][n]
__global__ __launch_bounds__(256) void stats_qd_k(const float* __restrict__ Q,
                                                  const int* __restrict__ idx,
                                                  double* __restrict__ sum,
                                                  double* __restrict__ sumsq) {
  int c = blockIdx.x, b = blockIdx.y;
  const float* Qp = Q + ((long)b * 256 + c) * 2048;
  const int* ip = idx + (long)b * 20480;
  float s = 0.f, s2 = 0.f;
  for (int m = threadIdx.x; m < 20480; m += 256) {
    float v = Qp[ip[m]] - Qp[m / 10];
    s += v; s2 = fmaf(v, v, s2);
  }
  __shared__ float ls[256], ls2[256];
  ls[threadIdx.x] = s; ls2[threadIdx.x] = s2;
  __syncthreads();
  for (int st = 128; st > 0; st >>= 1) {
    if (threadIdx.x < st) { ls[threadIdx.x] += ls[threadIdx.x + st]; ls2[threadIdx.x] += ls2[threadIdx.x + st]; }
    __syncthreads();
  }
  if (threadIdx.x == 0) { atomicAdd(&sum[c], (double)ls[0]); atomicAdd(&sumsq[c], (double)ls2[0]); }
}

// BN3 stats of virtual cx[b][c][n][k] = R[b][c][n] + S[b][c][idx]
__global__ __launch_bounds__(256) void stats_cx_k(const float* __restrict__ R,
                                                  const float* __restrict__ S,
                                                  const int* __restrict__ idx,
                                                  double* __restrict__ sum,
                                                  double* __restrict__ sumsq) {
  int c = blockIdx.x, b = blockIdx.y;
  const float* Rp = R + ((long)b * 512 + c) * 2048;
  const float* Sp = S + ((long)b * 512 + c) * 2048;
  const int* ip = idx + (long)b * 20480;
  float s = 0.f, s2 = 0.f;
  for (int m = threadIdx.x; m < 20480; m += 256) {
    float v = Rp[m / 10] + Sp[ip[m]];
    s += v; s2 = fmaf(v, v, s2);
  }
  __shared__ float ls[256], ls2[256];
  ls[threadIdx.x] = s; ls2[threadIdx.x] = s2;
  __syncthreads();
  for (int st = 128; st > 0; st >>= 1) {
    if (threadIdx.x < st) { ls[threadIdx.x] += ls[threadIdx.x + st]; ls2[threadIdx.x] += ls2[threadIdx.x + st]; }
    __syncthreads();
  }
  if (threadIdx.x == 0) { atomicAdd(&sum[c], (double)ls[0]); atomicAdd(&sumsq[c], (double)ls2[0]); }
}

__global__ void bnfin_k(const double* __restrict__ sum, const double* __restrict__ sumsq,
                        const float* __restrict__ g, const float* __restrict__ bb,
                        float* __restrict__ sc, float* __restrict__ sh, int C, double invcnt) {
  int c = blockIdx.x * 256 + threadIdx.x;
  if (c >= C) return;
  double mean = sum[c] * invcnt;
  double var = sumsq[c] * invcnt - mean * mean;
  float rstd = (float)(1.0 / sqrt(var + 1e-5));
  float scv = g[c] * rstd;
  sc[c] = scv;
  sh[c] = bb[c] - (float)mean * scv;
}

// per-batch chunk: w[o][n*10+k] -> softmax_k(lrelu01(sc[o]*w+sh[o])) in place
__global__ void softmax_c(float* __restrict__ w, const float* __restrict__ sc,
                          const float* __restrict__ sh) {
  int id = blockIdx.x * 256 + threadIdx.x;   // 512*2048
  if (id >= 512 * 2048) return;
  int o = id >> 11, n = id & 2047;
  float* p = w + (long)o * 20480 + n * 10;
  float a = sc[o], bsh = sh[o];
  float v[10], m = -1e30f;
#pragma unroll
  for (int k = 0; k < 10; ++k) {
    float x = fmaf(a, p[k], bsh);
    x = x >= 0.f ? x : 0.01f * x;
    v[k] = x; m = fmaxf(m, x);
  }
  float s = 0.f;
#pragma unroll
  for (int k = 0; k < 10; ++k) { v[k] = __expf(v[k] - m); s += v[k]; }
  float inv = 1.f / s;
#pragma unroll
  for (int k = 0; k < 10; ++k) p[k] = v[k] * inv;
}

// per-batch chunk: Xe[(c*10+k)][n] = lrelu01(sc[c]*(R[c][n]+S[c][j])+sh[c]) * wsm
__global__ void xe_c(const float* __restrict__ R, const float* __restrict__ S,
                     const int* __restrict__ idx, const float* __restrict__ wsm,
                     const float* __restrict__ sc, const float* __restrict__ sh,
                     float* __restrict__ Xe) {
  long id = (long)blockIdx.x * 256 + threadIdx.x;
  const long TOT = 5120L * 2048;
  if (id >= TOT) return;
  int n = (int)(id & 2047);
  int r = (int)(id >> 11);
  int c = r / 10, k = r % 10;
  int j = idx[n * 10 + k];
  float v = R[(long)c * 2048 + n] + S[(long)c * 2048 + j];
  v = fmaf(sc[c], v, sh[c]);
  v = v >= 0.f ? v : 0.01f * v;
  float wv = wsm[(long)c * 20480 + n * 10 + k];
  Xe[id] = v * wv;
}

__global__ void adain_k(float* __restrict__ x2, const float* __restrict__ ad2) {
  long id = (long)blockIdx.x * 256 + threadIdx.x;   // [b][c][n], c<512
  const long TOT = 8L * 512 * 2048;
  if (id >= TOT) return;
  int n = (int)(id & 2047);
  long t = id >> 11;
  int c = (int)(t & 511);
  int b = (int)(t >> 9);
  const float* A = ad2 + (long)b * 1024 * 2048;
  float ga = A[(long)c * 2048 + n];
  float be = A[(long)(512 + c) * 2048 + n];
  x2[id] = fmaf(ga, x2[id], be);
}

// ---------------- host ----------------
extern "C" void kernel_launch(void* const* d_in, const int* in_sizes, int n_in,
                              void* d_out, int out_size, void* d_ws, size_t ws_size,
                              hipStream_t stream) {
  (void)in_sizes; (void)n_in;
  const float* xin     = (const float*)d_in[0];
  const float* zin     = (const float*)d_in[1];
  const float* head_w1 = (const float*)d_in[2];
  const float* head_b1 = (const float*)d_in[3];
  const float* head_w2 = (const float*)d_in[4];
  const float* head_b2 = (const float*)d_in[5];
  const float* lat_w   = (const float*)d_in[22];
  const float* lat_b   = (const float*)d_in[23];
  const float* e2_w1   = (const float*)d_in[24];
  const float* e2_g1   = (const float*)d_in[26];
  const float* e2_bb1  = (const float*)d_in[27];
  const float* e2_w2   = (const float*)d_in[28];
  const float* e2_g2   = (const float*)d_in[30];
  const float* e2_bb2  = (const float*)d_in[31];
  const float* e2_xw   = (const float*)d_in[32];
  const float* e2_xg   = (const float*)d_in[34];
  const float* e2_xbb  = (const float*)d_in[35];
  const float* e2_ow   = (const float*)d_in[36];
  const float* e2_ob   = (const float*)d_in[37];
  const float* ad2_w   = (const float*)d_in[38];
  const float* ad2_b   = (const float*)d_in[39];
  const float* tail_w1 = (const float*)d_in[40];
  const float* tail_b1 = (const float*)d_in[41];
  const float* tail_w2 = (const float*)d_in[42];
  const float* tail_b2 = (const float*)d_in[43];
  const float* tail_w3 = (const float*)d_in[44];
  const float* tail_b3 = (const float*)d_in[45];
  float* out = (float*)d_out;

  // ---- arena (~245 MB; R5-proven budget) ----
  char* ws = (char*)d_ws;
  size_t off = 0;
  auto A = [&](size_t bytes) { size_t r = off; off += (bytes + 255) & ~(size_t)255; return r; };
  size_t oStats = A(20480);
  size_t oSc1 = A(1024), oSh1 = A(1024);
  size_t oSc2 = A(2048), oSh2 = A(2048);
  size_t oSc3 = A(2048), oSh3 = A(2048);
  size_t oXwA = A(512 * 128 * 4), oXwB = A(512 * 128 * 4);
  size_t oSq  = A(8L * 2048 * 4);
  size_t oIdx = A(8L * 2048 * 10 * 4);
  size_t oX1  = A(8L * 128 * 2048 * 4);
  size_t oQ   = A(8L * 256 * 2048 * 4);
  size_t oR   = A(8L * 512 * 2048 * 4);
  size_t oS   = A(8L * 512 * 2048 * 4);
  size_t oStyle = A(8L * 512 * 2048 * 4);
  size_t oX2  = A(8L * 512 * 2048 * 4);
  size_t oSL  = A(83886080 + 512);
  if (ws_size < off) {
    fill_k<<<(out_size + 255) / 256, 256, 0, stream>>>(out, (float)(ws_size >> 20), out_size);
    return;
  }

  double* sum1 = (double*)(ws + oStats);
  double* sumsq1 = sum1 + 256;
  double* sum2 = sumsq1 + 256;
  double* sumsq2 = sum2 + 512;
  double* sum3 = sumsq2 + 512;
  double* sumsq3 = sum3 + 512;
  float* sc1 = (float*)(ws + oSc1); float* sh1 = (float*)(ws + oSh1);
  float* sc2 = (float*)(ws + oSc2); float* sh2 = (float*)(ws + oSh2);
  float* sc3 = (float*)(ws + oSc3); float* sh3 = (float*)(ws + oSh3);
  float* xwA = (float*)(ws + oXwA); float* xwB = (float*)(ws + oXwB);
  float* sq = (float*)(ws + oSq);
  int* idx = (int*)(ws + oIdx);
  float* x1 = (float*)(ws + oX1);
  float* Q = (float*)(ws + oQ);
  float* R = (float*)(ws + oR);
  float* S = (float*)(ws + oS);
  float* style = (float*)(ws + oStyle);
  float* style1 = (float*)(ws + oX2);
  float* x2 = (float*)(ws + oX2);
  float* xz = (float*)(ws + oSL);
  float* dist = (float*)(ws + oSL);
  float* w2c = (float*)(ws + oSL);
  float* Xec = (float*)(ws + oSL + 41943040);
  float* ad2out = (float*)(ws + oSL);
  float* t1 = (float*)(ws + oSL);
  float* t2 = (float*)(ws + oSL + 41943040);

  hipMemsetAsync(ws + oStats, 0, 20480, stream);

  // ---- np-exact f32 head (FMA chains): xz -> style1 -> style -> x1 ----
  xz_k<<<(8L * 131 * 2048 + 255) / 256, 256, 0, stream>>>(xin, zin, xz);
  seqmm_k<1, 8><<<dim3(8, 64, 8), 256, 0, stream>>>(
      head_w1, xz, head_b1, style1, 131, 131L * 2048, 512L * 2048);
  seqmm_k<1, 8><<<dim3(8, 64, 8), 256, 0, stream>>>(
      head_w2, style1, head_b2, style, 512, 512L * 2048, 512L * 2048);
  seqmm_k<0, 8><<<dim3(8, 16, 8), 256, 0, stream>>>(
      lat_w, style, lat_b, x1, 512, 512L * 2048, 128L * 2048);

  // ---- np-exact kNN: sq (AVX512 npyv pairwise) + gram (FMA seq-c) + topk ----
  sqnp_k<<<dim3(8, 8), 256, 0, stream>>>(x1, sq);
  for (int b = 0; b < 8; ++b) {
    gramseq_k<<<dim3(8, 256), 256, 0, stream>>>(
        x1 + (long)b * 128 * 2048, sq + b * 2048, dist);
    topk_k<<<2048, 64, 0, stream>>>(dist, idx + (long)b * 20480);
  }

  // ---- Q = e2_w1 @ x1; BN1 stats; sc1/sh1 ----
  gemm_k<0, 0, 0><<<dim3(32, 4, 8), 256, 0, stream>>>(
      e2_w1, x1, nullptr, Q, 256, 128, 2048, 128L * 2048, 256L * 2048,
      nullptr, nullptr, 0.f, nullptr, 0, nullptr, nullptr);
  stats_qd_k<<<dim3(256, 8), 256, 0, stream>>>(Q, idx, sum1, sumsq1);
  bnfin_k<<<1, 256, 0, stream>>>(sum1, sumsq1, e2_g1, e2_bb1, sc1, sh1, 256, 1.0 / 163840.0);

  // ---- conv_x: R = (xwA-xwB)@x1, S = xwB@x1; BN3 stats ----
  xwsplit_k<<<(512 * 128 + 255) / 256, 256, 0, stream>>>(e2_xw, xwA, xwB);
  gemm_k<0, 0, 0><<<dim3(32, 8, 8), 256, 0, stream>>>(
      xwA, x1, nullptr, R, 512, 128, 2048, 128L * 2048, 512L * 2048,
      nullptr, nullptr, 0.f, nullptr, 0, nullptr, nullptr);
  gemm_k<0, 0, 0><<<dim3(32, 8, 8), 256, 0, stream>>>(
      xwB, x1, nullptr, S, 512, 128, 2048, 128L * 2048, 512L * 2048,
      nullptr, nullptr, 0.f, nullptr, 0, nullptr, nullptr);
  stats_cx_k<<<dim3(512, 8), 256, 0, stream>>>(R, S, idx, sum3, sumsq3);
  bnfin_k<<<2, 256, 0, stream>>>(sum3, sumsq3, e2_xg, e2_xbb, sc3, sh3, 512, 1.0 / 163840.0);

  // ---- BN2 stats: stats-only fused-gather GEMM pass ----
  gemm_k<2, 0, 1><<<dim3(320, 8, 8), 256, 0, stream>>>(
      e2_w2, Q, nullptr, nullptr, 512, 256, 20480, 256L * 2048, 0,
      sc1, sh1, 0.f, idx, 20480, sum2, sumsq2);
  bnfin_k<<<2, 256, 0, stream>>>(sum2, sumsq2, e2_g2, e2_bb2, sc2, sh2, 512, 1.0 / 163840.0);

  // ---- per-batch: w2 -> softmax -> Xe -> conv_out ----
  for (int b = 0; b < 8; ++b) {
    gemm_k<2, 0, 0><<<dim3(320, 8, 1), 256, 0, stream>>>(
        e2_w2, Q + (long)b * 256 * 2048, nullptr, w2c, 512, 256, 20480, 0, 0,
        sc1, sh1, 0.f, idx + (long)b * 20480, 0, nullptr, nullptr);
    softmax_c<<<(512 * 2048 + 255) / 256, 256, 0, stream>>>(w2c, sc2, sh2);
    xe_c<<<(5120L * 2048 + 255) / 256, 256, 0, stream>>>(
        R + (long)b * 512 * 2048, S + (long)b * 512 * 2048,
        idx + (long)b * 20480, w2c, sc3, sh3, Xec);
    gemm_k<0, 1, 0><<<dim3(32, 8, 1), 256, 0, stream>>>(
        e2_ow, Xec, e2_ob, x2 + (long)b * 512 * 2048, 512, 5120, 2048, 0, 0,
        nullptr, nullptr, 0.2f, nullptr, 0, nullptr, nullptr);
  }

  // ---- AdaIN2 ----
  gemm_k<0, 0, 0><<<dim3(32, 16, 8), 256, 0, stream>>>(
      ad2_w, style, ad2_b, ad2out, 1024, 512, 2048, 512L * 2048, 1024L * 2048,
      nullptr, nullptr, 0.f, nullptr, 0, nullptr, nullptr);
  adain_k<<<(8L * 512 * 2048 + 255) / 256, 256, 0, stream>>>(x2, ad2out);

  // ---- tail ----
  gemm_k<0, 1, 0><<<dim3(32, 4, 8), 256, 0, stream>>>(
      tail_w1, x2, tail_b1, t1, 256, 512, 2048, 512L * 2048, 256L * 2048,
      nullptr, nullptr, 0.01f, nullptr, 0, nullptr, nullptr);
  gemm_k<0, 1, 0><<<dim3(32, 1, 8), 256, 0, stream>>>(
      tail_w2, t1, tail_b2, t2, 64, 256, 2048, 256L * 2048, 64L * 2048,
      nullptr, nullptr, 0.01f, nullptr, 0, nullptr, nullptr);
  gemm_k<0, 2, 0><<<dim3(32, 1, 8), 256, 0, stream>>>(
      tail_w3, t2, tail_b3, out, 3, 64, 2048, 64L * 2048, 3L * 2048,
      nullptr, nullptr, 0.f, nullptr, 0, nullptr, nullptr);
}

// Round 11
// 5171.062 us; speedup vs baseline: 2.0825x; 2.0825x over previous
//
#include <hip/hip_runtime.h>
#include <hip/hip_bf16.h>

// SP_DecoderLight forward, MI355X. Round 11: f32 structural optimization.
// R10 PASSED (10.77ms). Profile: XMODE2 gather GEMMs latency-bound (VALU 42%,
// MfmaUtil 0, HBM 1%). Fixes: (1) materialize G (gathered+BN1+lrelu) once per
// batch -> stats/w2 become coalesced GEMMs (bit-identical w2 values);
// (2) 128x128-tile 8x8-microtile f32 GEMM (FMA-issue-bound) for big GEMMs;
// (3) conv_out split-K x8 + deterministic reduce. kNN-exact path untouched.

using bf16 = __hip_bfloat16;

// ---------------- np-exact sequential GEMM (FMA chain, c-ascending) -------
template<int ACT, int OG>
__global__ __launch_bounds__(256) void seqmm_k(
    const float* __restrict__ W, const float* __restrict__ X,
    const float* __restrict__ bias, float* __restrict__ Out,
    int C, long sXb, long sOb)
{
  int n = blockIdx.x * 256 + threadIdx.x;
  int o0 = blockIdx.y * OG;
  const float* Xb = X + (long)blockIdx.z * sXb;
  float acc[OG];
#pragma unroll
  for (int g = 0; g < OG; ++g) acc[g] = 0.f;
  for (int c = 0; c < C; ++c) {
    float xv = Xb[(long)c * 2048 + n];
#pragma unroll
    for (int g = 0; g < OG; ++g)
      acc[g] = fmaf(W[(long)(o0 + g) * C + c], xv, acc[g]);
  }
  float* Ob = Out + (long)blockIdx.z * sOb;
#pragma unroll
  for (int g = 0; g < OG; ++g) {
    float v = __fadd_rn(acc[g], bias[o0 + g]);
    if (ACT) v = v >= 0.f ? v : __fmul_rn(0.01f, v);
    Ob[(long)(o0 + g) * 2048 + n] = v;
  }
}

// numpy npyv(AVX512) pairwise sum of squares (exact golden realization)
__global__ void sqnp_k(const float* __restrict__ x1, float* __restrict__ sq) {
  int n = blockIdx.x * 256 + threadIdx.x;
  int b = blockIdx.y;
  const float* p = x1 + (long)b * 128 * 2048 + n;
  float r[4][16];
#pragma unroll
  for (int v = 0; v < 4; ++v)
#pragma unroll
    for (int l = 0; l < 16; ++l) {
      float x = p[(long)(16 * v + l) * 2048];
      r[v][l] = __fmul_rn(x, x);
    }
#pragma unroll
  for (int v = 0; v < 4; ++v)
#pragma unroll
    for (int l = 0; l < 16; ++l) {
      float x = p[(long)(64 + 16 * v + l) * 2048];
      r[v][l] = __fadd_rn(r[v][l], __fmul_rn(x, x));
    }
  float u[16];
#pragma unroll
  for (int l = 0; l < 16; ++l)
    u[l] = __fadd_rn(__fadd_rn(r[0][l], r[1][l]), __fadd_rn(r[2][l], r[3][l]));
  float b8[8];
#pragma unroll
  for (int l = 0; l < 8; ++l) b8[l] = __fadd_rn(u[l], u[l + 8]);
  float c4[4];
#pragma unroll
  for (int l = 0; l < 4; ++l) c4[l] = __fadd_rn(b8[l], b8[l + 4]);
  float d0 = __fadd_rn(c4[0], c4[2]);
  float d1 = __fadd_rn(c4[1], c4[3]);
  sq[b * 2048 + n] = __fadd_rn(d0, d1);
}

// np-exact gram (FMA chain)
__global__ __launch_bounds__(256) void gramseq_k(const float* __restrict__ A,
                                                 const float* __restrict__ sqb,
                                                 float* __restrict__ D) {
  int m = blockIdx.x * 256 + threadIdx.x;
  int n0 = blockIdx.y * 8;
  float g[8];
#pragma unroll
  for (int j = 0; j < 8; ++j) g[j] = 0.f;
  for (int c = 0; c < 128; ++c) {
    float xm = A[(long)c * 2048 + m];
#pragma unroll
    for (int j = 0; j < 8; ++j)
      g[j] = fmaf(A[(long)c * 2048 + n0 + j], xm, g[j]);
  }
  float sm = sqb[m];
#pragma unroll
  for (int j = 0; j < 8; ++j) {
    float t1 = __fadd_rn(sqb[n0 + j], sm);
    D[(long)(n0 + j) * 2048 + m] = __fsub_rn(t1, __fmul_rn(2.0f, g[j]));
  }
}

// ---------------- f32 tiled GEMM 64x64 (small GEMMs) ----------------
template<int ACT>
__global__ __launch_bounds__(256) void gemm_k(
    const float* __restrict__ W, const float* __restrict__ X,
    const float* __restrict__ bias, float* __restrict__ Out,
    int O, int K, int N, long sXb, long sOb, float slope)
{
  const float* Xb = X + (long)blockIdx.z * sXb;
  int n0 = blockIdx.x * 64, o0 = blockIdx.y * 64;
  __shared__ float Ws[16][68];
  __shared__ float Xs[16][68];
  int t = threadIdx.x, tx = t & 15, ty = t >> 4;
  float acc[16] = {};
  for (int k0 = 0; k0 < K; k0 += 16) {
#pragma unroll
    for (int i = 0; i < 4; ++i) {
      int l = t + i * 256, oo = l >> 4, kk = l & 15;
      int o = o0 + oo, k = k0 + kk;
      float v = 0.f;
      if (o < O && k < K) v = W[(long)o * K + k];
      Ws[kk][oo] = v;
    }
#pragma unroll
    for (int i = 0; i < 4; ++i) {
      int kk = (t >> 6) + i * 4, nn = t & 63;
      int k = k0 + kk;
      float v = 0.f;
      if (k < K) v = Xb[(long)k * N + n0 + nn];
      Xs[kk][nn] = v;
    }
    __syncthreads();
#pragma unroll
    for (int kk = 0; kk < 16; ++kk) {
      float a0 = Ws[kk][ty * 4 + 0], a1 = Ws[kk][ty * 4 + 1];
      float a2 = Ws[kk][ty * 4 + 2], a3 = Ws[kk][ty * 4 + 3];
      float b0 = Xs[kk][tx * 4 + 0], b1 = Xs[kk][tx * 4 + 1];
      float b2 = Xs[kk][tx * 4 + 2], b3 = Xs[kk][tx * 4 + 3];
      acc[0] = fmaf(a0, b0, acc[0]);   acc[1] = fmaf(a0, b1, acc[1]);
      acc[2] = fmaf(a0, b2, acc[2]);   acc[3] = fmaf(a0, b3, acc[3]);
      acc[4] = fmaf(a1, b0, acc[4]);   acc[5] = fmaf(a1, b1, acc[5]);
      acc[6] = fmaf(a1, b2, acc[6]);   acc[7] = fmaf(a1, b3, acc[7]);
      acc[8] = fmaf(a2, b0, acc[8]);   acc[9] = fmaf(a2, b1, acc[9]);
      acc[10] = fmaf(a2, b2, acc[10]); acc[11] = fmaf(a2, b3, acc[11]);
      acc[12] = fmaf(a3, b0, acc[12]); acc[13] = fmaf(a3, b1, acc[13]);
      acc[14] = fmaf(a3, b2, acc[14]); acc[15] = fmaf(a3, b3, acc[15]);
    }
    __syncthreads();
  }
#pragma unroll
  for (int i = 0; i < 4; ++i) {
    int o = o0 + ty * 4 + i;
    if (o < O) {
      float bv = bias ? bias[o] : 0.f;
#pragma unroll
      for (int j = 0; j < 4; ++j) {
        float v = acc[i * 4 + j] + bv;
        if constexpr (ACT == 1) v = v >= 0.f ? v : slope * v;
        if constexpr (ACT == 2) v = tanhf(v);
        Ob_store:
        Out[(long)blockIdx.z * sOb + (long)o * N + n0 + tx * 4 + j] = v;
      }
    }
  }
}

// ---------------- f32 tiled GEMM 128x128, 8x8 microtile ----------------
// STATS=1: accumulate per-o sum/sumsq (doubles), no store.
// SPLITK=1: kOff = z*kLen, X fixed, Out += z*sOz (partials).
// else: X += z*sXz, Out += z*sOz.
template<int STATS, int SPLITK>
__global__ __launch_bounds__(256) void gemm2_k(
    const float* __restrict__ W, const float* __restrict__ X,
    const float* __restrict__ bias, float* __restrict__ Out,
    int O, int K, int N, int kLen, long sXz, long sOz,
    double* __restrict__ gsum, double* __restrict__ gsq)
{
  int kOff = 0;
  if constexpr (SPLITK) { kOff = blockIdx.z * kLen; }
  else { X += (long)blockIdx.z * sXz; }
  int n0 = blockIdx.x * 128, o0 = blockIdx.y * 128;
  __shared__ float Ws[8][132];
  __shared__ float Xs[8][132];
  __shared__ float ssum[128], ssq[128];
  int t = threadIdx.x, tx = t & 15, ty = t >> 4;
  float acc[8][8] = {};
  for (int k0 = kOff; k0 < kOff + kLen; k0 += 8) {
    {
      int kk = t & 7, oo0 = t >> 3;
#pragma unroll
      for (int i = 0; i < 4; ++i) {
        int oo = oo0 + i * 32;
        Ws[kk][oo] = W[(long)(o0 + oo) * K + k0 + kk];
      }
    }
    {
      int nn = t & 127, kk0 = t >> 7;
#pragma unroll
      for (int i = 0; i < 4; ++i) {
        int kk = kk0 + i * 2;
        Xs[kk][nn] = X[(long)(k0 + kk) * N + n0 + nn];
      }
    }
    __syncthreads();
#pragma unroll
    for (int kk = 0; kk < 8; ++kk) {
      float a[8], bx[8];
#pragma unroll
      for (int i = 0; i < 8; ++i) a[i] = Ws[kk][ty * 8 + i];
#pragma unroll
      for (int j = 0; j < 8; ++j) bx[j] = Xs[kk][tx * 8 + j];
#pragma unroll
      for (int i = 0; i < 8; ++i)
#pragma unroll
        for (int j = 0; j < 8; ++j)
          acc[i][j] = fmaf(a[i], bx[j], acc[i][j]);
    }
    __syncthreads();
  }
  if constexpr (STATS) {
    if (t < 128) { ssum[t] = 0.f; ssq[t] = 0.f; }
    __syncthreads();
#pragma unroll
    for (int i = 0; i < 8; ++i) {
      float s = 0.f, s2 = 0.f;
#pragma unroll
      for (int j = 0; j < 8; ++j) { float v = acc[i][j]; s += v; s2 = fmaf(v, v, s2); }
      atomicAdd(&ssum[ty * 8 + i], s);
      atomicAdd(&ssq[ty * 8 + i], s2);
    }
    __syncthreads();
    if (t < 128) {
      atomicAdd(&gsum[o0 + t], (double)ssum[t]);
      atomicAdd(&gsq[o0 + t], (double)ssq[t]);
    }
  } else {
    float* Ob = Out + (long)blockIdx.z * sOz;
#pragma unroll
    for (int i = 0; i < 8; ++i) {
      int o = o0 + ty * 8 + i;
      float bv = bias ? bias[o] : 0.f;
#pragma unroll
      for (int j = 0; j < 8; ++j)
        Ob[(long)o * N + n0 + tx * 8 + j] = acc[i][j] + bv;
    }
  }
}

// ---------------- small kernels ----------------
__global__ void fill_k(float* __restrict__ out, float v, int n) {
  int id = blockIdx.x * 256 + threadIdx.x;
  if (id < n) out[id] = v;
}

__global__ void xz_k(const float* __restrict__ x, const float* __restrict__ z,
                     float* __restrict__ xz) {
  long id = (long)blockIdx.x * 256 + threadIdx.x;
  const long TOT = 8L * 131 * 2048;
  if (id >= TOT) return;
  int n = (int)(id % 2048);
  int c = (int)((id / 2048) % 131);
  int b = (int)(id / (131L * 2048));
  float v = (c < 3) ? x[((long)b * 3 + c) * 2048 + n]
                    : z[((long)b * 128 + (c - 3)) * 2048 + n];
  xz[id] = v;
}

__global__ void xwsplit_k(const float* __restrict__ xw, float* __restrict__ A,
                          float* __restrict__ Bm) {
  int id = blockIdx.x * 256 + threadIdx.x;
  if (id >= 512 * 128) return;
  int o = id / 128, c = id % 128;
  float a = xw[o * 256 + c];
  float b = xw[o * 256 + 128 + c];
  A[id] = a - b;
  Bm[id] = b;
}

// per-batch: 11 smallest ascending; rank0=self.
__global__ __launch_bounds__(64) void topk_k(const float* __restrict__ dist,
                                             int* __restrict__ idx) {
  int n = blockIdx.x;
  const float* row = dist + (long)n * 2048;
  __shared__ float vals[2048];
  int lane = threadIdx.x;
  for (int i = lane; i < 2048; i += 64) vals[i] = row[i];
  __syncthreads();
  const float INF = __builtin_inff();
  for (int r = 0; r < 11; ++r) {
    float v = INF; int mi = 0x7fffffff;
    for (int i = lane; i < 2048; i += 64) {
      float xv = vals[i];
      if (xv < v) { v = xv; mi = i; }
    }
    for (int off = 32; off; off >>= 1) {
      float ov = __shfl_xor(v, off);
      int om = __shfl_xor(mi, off);
      if (ov < v || (ov == v && om < mi)) { v = ov; mi = om; }
    }
    if (mi < 0 || mi > 2047) mi = n;
    if (lane == 0) {
      if (r > 0) idx[n * 10 + (r - 1)] = mi;
      vals[mi] = INF;
    }
    __syncthreads();
  }
}

// G[c][m] = lrelu01(sc1[c]*(Q[c][idx[m]] - Q[c][m/10]) + sh1[c])  (per batch)
__global__ void g_k(const float* __restrict__ Q, const int* __restrict__ idx,
                    const float* __restrict__ sc, const float* __restrict__ sh,
                    float* __restrict__ G) {
  long id = (long)blockIdx.x * 256 + threadIdx.x;
  const long TOT = 256L * 20480;
  if (id >= TOT) return;
  int m = (int)(id % 20480);
  int c = (int)(id / 20480);
  int j = idx[m];
  int n = m / 10;
  const float* Qc = Q + (long)c * 2048;
  float v = fmaf(sc[c], Qc[j] - Qc[n], sh[c]);
  G[id] = v >= 0.f ? v : 0.01f * v;
}

// x2[o][n] = lrelu02( sum_{s<8} P[s][o][n] + bias[o] )
__global__ void redk_k(const float* __restrict__ P, const float* __restrict__ bias,
                       float* __restrict__ xo) {
  int id = blockIdx.x * 256 + threadIdx.x;
  if (id >= 512 * 2048) return;
  int o = id >> 11;
  float s = 0.f;
#pragma unroll
  for (int sp = 0; sp < 8; ++sp) s += P[(long)sp * 512 * 2048 + id];
  s += bias[o];
  xo[id] = s >= 0.f ? s : 0.2f * s;
}

// BN1 stats of virtual cw1 = Q[idx]-Q[n]
__global__ __launch_bounds__(256) void stats_qd_k(const float* __restrict__ Q,
                                                  const int* __restrict__ idx,
                                                  double* __restrict__ sum,
                                                  double* __restrict__ sumsq) {
  int c = blockIdx.x, b = blockIdx.y;
  const float* Qp = Q + ((long)b * 256 + c) * 2048;
  const int* ip = idx + (long)b * 20480;
  float s = 0.f, s2 = 0.f;
  for (int m = threadIdx.x; m < 20480; m += 256) {
    float v = Qp[ip[m]] - Qp[m / 10];
    s += v; s2 = fmaf(v, v, s2);
  }
  __shared__ float ls[256], ls2[256];
  ls[threadIdx.x] = s; ls2[threadIdx.x] = s2;
  __syncthreads();
  for (int st = 128; st > 0; st >>= 1) {
    if (threadIdx.x < st) { ls[threadIdx.x] += ls[threadIdx.x + st]; ls2[threadIdx.x] += ls2[threadIdx.x + st]; }
    __syncthreads();
  }
  if (threadIdx.x == 0) { atomicAdd(&sum[c], (double)ls[0]); atomicAdd(&sumsq[c], (double)ls2[0]); }
}

// BN3 stats of virtual cx = R[n] + S[idx]
__global__ __launch_bounds__(256) void stats_cx_k(const float* __restrict__ R,
                                                  const float* __restrict__ S,
                                                  const int* __restrict__ idx,
                                                  double* __restrict__ sum,
                                                  double* __restrict__ sumsq) {
  int c = blockIdx.x, b = blockIdx.y;
  const float* Rp = R + ((long)b * 512 + c) * 2048;
  const float* Sp = S + ((long)b * 512 + c) * 2048;
  const int* ip = idx + (long)b * 20480;
  float s = 0.f, s2 = 0.f;
  for (int m = threadIdx.x; m < 20480; m += 256) {
    float v = Rp[m / 10] + Sp[ip[m]];
    s += v; s2 = fmaf(v, v, s2);
  }
  __shared__ float ls[256], ls2[256];
  ls[threadIdx.x] = s; ls2[threadIdx.x] = s2;
  __syncthreads();
  for (int st = 128; st > 0; st >>= 1) {
    if (threadIdx.x < st) { ls[threadIdx.x] += ls[threadIdx.x + st]; ls2[threadIdx.x] += ls2[threadIdx.x + st]; }
    __syncthreads();
  }
  if (threadIdx.x == 0) { atomicAdd(&sum[c], (double)ls[0]); atomicAdd(&sumsq[c], (double)ls2[0]); }
}

__global__ void bnfin_k(const double* __restrict__ sum, const double* __restrict__ sumsq,
                        const float* __restrict__ g, const float* __restrict__ bb,
                        float* __restrict__ sc, float* __restrict__ sh, int C, double invcnt) {
  int c = blockIdx.x * 256 + threadIdx.x;
  if (c >= C) return;
  double mean = sum[c] * invcnt;
  double var = sumsq[c] * invcnt - mean * mean;
  float rstd = (float)(1.0 / sqrt(var + 1e-5));
  float scv = g[c] * rstd;
  sc[c] = scv;
  sh[c] = bb[c] - (float)mean * scv;
}

// per-batch: w[o][n*10+k] -> softmax_k(lrelu01(sc[o]*w+sh[o])) in place
__global__ void softmax_c(float* __restrict__ w, const float* __restrict__ sc,
                          const float* __restrict__ sh) {
  int id = blockIdx.x * 256 + threadIdx.x;
  if (id >= 512 * 2048) return;
  int o = id >> 11, n = id & 2047;
  float* p = w + (long)o * 20480 + n * 10;
  float a = sc[o], bsh = sh[o];
  float v[10], m = -1e30f;
#pragma unroll
  for (int k = 0; k < 10; ++k) {
    float x = fmaf(a, p[k], bsh);
    x = x >= 0.f ? x : 0.01f * x;
    v[k] = x; m = fmaxf(m, x);
  }
  float s = 0.f;
#pragma unroll
  for (int k = 0; k < 10; ++k) { v[k] = __expf(v[k] - m); s += v[k]; }
  float inv = 1.f / s;
#pragma unroll
  for (int k = 0; k < 10; ++k) p[k] = v[k] * inv;
}

// per-batch: Xe[(c*10+k)][n] = lrelu01(sc3*(R+S[idx])+sh3) * wsm
__global__ void xe_c(const float* __restrict__ R, const float* __restrict__ S,
                     const int* __restrict__ idx, const float* __restrict__ wsm,
                     const float* __restrict__ sc, const float* __restrict__ sh,
                     float* __restrict__ Xe) {
  long id = (long)blockIdx.x * 256 + threadIdx.x;
  const long TOT = 5120L * 2048;
  if (id >= TOT) return;
  int n = (int)(id & 2047);
  int r = (int)(id >> 11);
  int c = r / 10, k = r % 10;
  int j = idx[n * 10 + k];
  float v = R[(long)c * 2048 + n] + S[(long)c * 2048 + j];
  v = fmaf(sc[c], v, sh[c]);
  v = v >= 0.f ? v : 0.01f * v;
  float wv = wsm[(long)c * 20480 + n * 10 + k];
  Xe[id] = v * wv;
}

__global__ void adain_k(float* __restrict__ x2, const float* __restrict__ ad2) {
  long id = (long)blockIdx.x * 256 + threadIdx.x;
  const long TOT = 8L * 512 * 2048;
  if (id >= TOT) return;
  int n = (int)(id & 2047);
  long t = id >> 11;
  int c = (int)(t & 511);
  int b = (int)(t >> 9);
  const float* A = ad2 + (long)b * 1024 * 2048;
  float ga = A[(long)c * 2048 + n];
  float be = A[(long)(512 + c) * 2048 + n];
  x2[id] = fmaf(ga, x2[id], be);
}

// ---------------- host ----------------
extern "C" void kernel_launch(void* const* d_in, const int* in_sizes, int n_in,
                              void* d_out, int out_size, void* d_ws, size_t ws_size,
                              hipStream_t stream) {
  (void)in_sizes; (void)n_in;
  const float* xin     = (const float*)d_in[0];
  const float* zin     = (const float*)d_in[1];
  const float* head_w1 = (const float*)d_in[2];
  const float* head_b1 = (const float*)d_in[3];
  const float* head_w2 = (const float*)d_in[4];
  const float* head_b2 = (const float*)d_in[5];
  const float* lat_w   = (const float*)d_in[22];
  const float* lat_b   = (const float*)d_in[23];
  const float* e2_w1   = (const float*)d_in[24];
  const float* e2_g1   = (const float*)d_in[26];
  const float* e2_bb1  = (const float*)d_in[27];
  const float* e2_w2   = (const float*)d_in[28];
  const float* e2_g2   = (const float*)d_in[30];
  const float* e2_bb2  = (const float*)d_in[31];
  const float* e2_xw   = (const float*)d_in[32];
  const float* e2_xg   = (const float*)d_in[34];
  const float* e2_xbb  = (const float*)d_in[35];
  const float* e2_ow   = (const float*)d_in[36];
  const float* e2_ob   = (const float*)d_in[37];
  const float* ad2_w   = (const float*)d_in[38];
  const float* ad2_b   = (const float*)d_in[39];
  const float* tail_w1 = (const float*)d_in[40];
  const float* tail_b1 = (const float*)d_in[41];
  const float* tail_w2 = (const float*)d_in[42];
  const float* tail_b2 = (const float*)d_in[43];
  const float* tail_w3 = (const float*)d_in[44];
  const float* tail_b3 = (const float*)d_in[45];
  float* out = (float*)d_out;

  // ---- arena (~245 MB; proven budget) ----
  char* ws = (char*)d_ws;
  size_t off = 0;
  auto A = [&](size_t bytes) { size_t r = off; off += (bytes + 255) & ~(size_t)255; return r; };
  size_t oStats = A(20480);
  size_t oSc1 = A(1024), oSh1 = A(1024);
  size_t oSc2 = A(2048), oSh2 = A(2048);
  size_t oSc3 = A(2048), oSh3 = A(2048);
  size_t oXwA = A(512 * 128 * 4), oXwB = A(512 * 128 * 4);
  size_t oSq  = A(8L * 2048 * 4);
  size_t oIdx = A(8L * 2048 * 10 * 4);
  size_t oX1  = A(8L * 128 * 2048 * 4);
  size_t oQ   = A(8L * 256 * 2048 * 4);
  size_t oR   = A(8L * 512 * 2048 * 4);
  size_t oS   = A(8L * 512 * 2048 * 4);
  size_t oStyle = A(8L * 512 * 2048 * 4);
  size_t oX2  = A(8L * 512 * 2048 * 4);
  size_t oSL  = A(83886080 + 512);
  if (ws_size < off) {
    fill_k<<<(out_size + 255) / 256, 256, 0, stream>>>(out, (float)(ws_size >> 20), out_size);
    return;
  }

  double* sum1 = (double*)(ws + oStats);
  double* sumsq1 = sum1 + 256;
  double* sum2 = sumsq1 + 256;
  double* sumsq2 = sum2 + 512;
  double* sum3 = sumsq2 + 512;
  double* sumsq3 = sum3 + 512;
  float* sc1 = (float*)(ws + oSc1); float* sh1 = (float*)(ws + oSh1);
  float* sc2 = (float*)(ws + oSc2); float* sh2 = (float*)(ws + oSh2);
  float* sc3 = (float*)(ws + oSc3); float* sh3 = (float*)(ws + oSh3);
  float* xwA = (float*)(ws + oXwA); float* xwB = (float*)(ws + oXwB);
  float* sq = (float*)(ws + oSq);
  int* idx = (int*)(ws + oIdx);
  float* x1 = (float*)(ws + oX1);
  float* Q = (float*)(ws + oQ);
  float* R = (float*)(ws + oR);
  float* S = (float*)(ws + oS);
  float* style = (float*)(ws + oStyle);
  float* style1 = (float*)(ws + oX2);
  float* x2 = (float*)(ws + oX2);
  // SL (84MB) time-share:
  //  dist(16.8M)@0 -> per-batch: G(21M)@0 | w2c(42M)@42M ; Xe(42M)@0 over G ;
  //  P(33.5M)@42M over w2c -> ad2out(67M)@0 -> t1@0 + t2@20M
  char* SL = ws + oSL;
  float* xz = (float*)(SL);
  float* dist = (float*)(SL);
  float* G = (float*)(SL);
  float* w2c = (float*)(SL + 41943040);
  float* Xec = (float*)(SL);
  float* P = (float*)(SL + 41943040);
  float* ad2out = (float*)(SL);
  float* t1 = (float*)(SL);
  float* t2 = (float*)(SL + 20971520);

  hipMemsetAsync(ws + oStats, 0, 20480, stream);

  // ---- np-exact f32 head (FMA chains): xz -> style1 -> style -> x1 ----
  xz_k<<<(8L * 131 * 2048 + 255) / 256, 256, 0, stream>>>(xin, zin, xz);
  seqmm_k<1, 8><<<dim3(8, 64, 8), 256, 0, stream>>>(
      head_w1, xz, head_b1, style1, 131, 131L * 2048, 512L * 2048);
  seqmm_k<1, 8><<<dim3(8, 64, 8), 256, 0, stream>>>(
      head_w2, style1, head_b2, style, 512, 512L * 2048, 512L * 2048);
  seqmm_k<0, 8><<<dim3(8, 16, 8), 256, 0, stream>>>(
      lat_w, style, lat_b, x1, 512, 512L * 2048, 128L * 2048);

  // ---- np-exact kNN (unchanged) ----
  sqnp_k<<<dim3(8, 8), 256, 0, stream>>>(x1, sq);
  for (int b = 0; b < 8; ++b) {
    gramseq_k<<<dim3(8, 256), 256, 0, stream>>>(
        x1 + (long)b * 128 * 2048, sq + b * 2048, dist);
    topk_k<<<2048, 64, 0, stream>>>(dist, idx + (long)b * 20480);
  }

  // ---- Q = e2_w1 @ x1; BN1 stats; sc1/sh1 ----
  gemm_k<0><<<dim3(32, 4, 8), 256, 0, stream>>>(
      e2_w1, x1, nullptr, Q, 256, 128, 2048, 128L * 2048, 256L * 2048, 0.f);
  stats_qd_k<<<dim3(256, 8), 256, 0, stream>>>(Q, idx, sum1, sumsq1);
  bnfin_k<<<1, 256, 0, stream>>>(sum1, sumsq1, e2_g1, e2_bb1, sc1, sh1, 256, 1.0 / 163840.0);

  // ---- conv_x: R, S; BN3 stats ----
  xwsplit_k<<<(512 * 128 + 255) / 256, 256, 0, stream>>>(e2_xw, xwA, xwB);
  gemm_k<0><<<dim3(32, 8, 8), 256, 0, stream>>>(
      xwA, x1, nullptr, R, 512, 128, 2048, 128L * 2048, 512L * 2048, 0.f);
  gemm_k<0><<<dim3(32, 8, 8), 256, 0, stream>>>(
      xwB, x1, nullptr, S, 512, 128, 2048, 128L * 2048, 512L * 2048, 0.f);
  stats_cx_k<<<dim3(512, 8), 256, 0, stream>>>(R, S, idx, sum3, sumsq3);
  bnfin_k<<<2, 256, 0, stream>>>(sum3, sumsq3, e2_xg, e2_xbb, sc3, sh3, 512, 1.0 / 163840.0);

  // ---- BN2 stats: per-batch G materialization + coalesced stats-GEMM ----
  for (int b = 0; b < 8; ++b) {
    g_k<<<20480, 256, 0, stream>>>(Q + (long)b * 256 * 2048, idx + (long)b * 20480,
                                   sc1, sh1, G);
    gemm2_k<1, 0><<<dim3(160, 4, 1), 256, 0, stream>>>(
        e2_w2, G, nullptr, nullptr, 512, 256, 20480, 256, 0, 0, sum2, sumsq2);
  }
  bnfin_k<<<2, 256, 0, stream>>>(sum2, sumsq2, e2_g2, e2_bb2, sc2, sh2, 512, 1.0 / 163840.0);

  // ---- per-batch: G -> w2 -> softmax -> Xe -> conv_out(split-K) -> x2 ----
  for (int b = 0; b < 8; ++b) {
    g_k<<<20480, 256, 0, stream>>>(Q + (long)b * 256 * 2048, idx + (long)b * 20480,
                                   sc1, sh1, G);
    gemm2_k<0, 0><<<dim3(160, 4, 1), 256, 0, stream>>>(
        e2_w2, G, nullptr, w2c, 512, 256, 20480, 256, 0, 0, nullptr, nullptr);
    softmax_c<<<(512 * 2048 + 255) / 256, 256, 0, stream>>>(w2c, sc2, sh2);
    xe_c<<<(5120L * 2048 + 255) / 256, 256, 0, stream>>>(
        R + (long)b * 512 * 2048, S + (long)b * 512 * 2048,
        idx + (long)b * 20480, w2c, sc3, sh3, Xec);
    gemm2_k<0, 1><<<dim3(16, 4, 8), 256, 0, stream>>>(
        e2_ow, Xec, nullptr, P, 512, 5120, 2048, 640, 0, 512L * 2048,
        nullptr, nullptr);
    redk_k<<<(512 * 2048 + 255) / 256, 256, 0, stream>>>(
        P, e2_ob, x2 + (long)b * 512 * 2048);
  }

  // ---- AdaIN2 (gemm2, z=batch) ----
  gemm2_k<0, 0><<<dim3(16, 8, 8), 256, 0, stream>>>(
      ad2_w, style, ad2_b, ad2out, 1024, 512, 2048, 512, 512L * 2048, 1024L * 2048,
      nullptr, nullptr);
  adain_k<<<(8L * 512 * 2048 + 255) / 256, 256, 0, stream>>>(x2, ad2out);

  // ---- tail ----
  gemm_k<1><<<dim3(32, 4, 8), 256, 0, stream>>>(
      tail_w1, x2, tail_b1, t1, 256, 512, 2048, 512L * 2048, 256L * 2048, 0.01f);
  gemm_k<1><<<dim3(32, 1, 8), 256, 0, stream>>>(
      tail_w2, t1, tail_b2, t2, 64, 256, 2048, 256L * 2048, 64L * 2048, 0.01f);
  gemm_k<2><<<dim3(32, 1, 8), 256, 0, stream>>>(
      tail_w3, t2, tail_b3, out, 3, 64, 2048, 64L * 2048, 3L * 2048, 0.f);
}